// Round 2
// baseline (496.384 us; speedup 1.0000x reference)
//
#include <hip/hip_runtime.h>

#define B_ 4
#define S_ 4096
#define D_ 1024
#define H_ 16
#define DH 64
#define CHUNK 64
#define NC (S_ / CHUNK)   // 64 chunks
#define BH (B_ * H_)      // 64 (b,h) sequences
#define STATE_N 4160      // 64*64 S entries + 64 z entries
#define EPS 1e-6f

typedef __bf16 bf16;
typedef __bf16 bf16x8 __attribute__((ext_vector_type(8)));
typedef __bf16 bf16x4 __attribute__((ext_vector_type(4)));
typedef float v4f __attribute__((ext_vector_type(4)));

#define MFMA16(a, b, c) __builtin_amdgcn_mfma_f32_16x16x32_bf16(a, b, c, 0, 0, 0)

// ---------------------------------------------------------------------------
// fp32 -> bf16 convert (x): 8 elems/thread, vectorized.
// ---------------------------------------------------------------------------
__global__ __launch_bounds__(256) void cvt_f32_bf16(const float* __restrict__ in,
                                                    bf16* __restrict__ out) {
  const size_t i = ((size_t)blockIdx.x * 256 + threadIdx.x) * 8;
  float4 a = *(const float4*)(in + i);
  float4 b = *(const float4*)(in + i + 4);
  bf16x8 o;
  o[0] = (bf16)a.x; o[1] = (bf16)a.y; o[2] = (bf16)a.z; o[3] = (bf16)a.w;
  o[4] = (bf16)b.x; o[5] = (bf16)b.y; o[6] = (bf16)b.z; o[7] = (bf16)b.w;
  *(bf16x8*)(out + i) = o;
}

// ---------------------------------------------------------------------------
// Weight transpose + fp32->bf16: out[n*1024+k] = (bf16)in[k*1024+n]
// ---------------------------------------------------------------------------
__global__ __launch_bounds__(256) void transpose_w(const float* __restrict__ in,
                                                   bf16* __restrict__ out) {
  __shared__ float tile[32][33];
  const int bx = blockIdx.x * 32, by = blockIdx.y * 32;
  const int tx = threadIdx.x & 31, ty = threadIdx.x >> 5;  // 32 x 8
#pragma unroll
  for (int i = 0; i < 32; i += 8)
    tile[ty + i][tx] = in[(size_t)(by + ty + i) * D_ + bx + tx];
  __syncthreads();
#pragma unroll
  for (int i = 0; i < 32; i += 8)
    out[(size_t)(bx + ty + i) * D_ + by + tx] = (bf16)tile[tx][ty + i];
}

// ---------------------------------------------------------------------------
// NT GEMM: C[M,N] = act(A[M,K] @ BT[N,K]^T), M=16384, N=K=1024, bf16 in,
// fp32 accum.  act=1 applies phi(x)=elu(x)+1.  Output: bf16 (Cb) unless
// Cf != nullptr (fp32, for the final Wo GEMM).
// Block 256 thr (4 waves), tile 128x128, BK=32.
// ---------------------------------------------------------------------------
__global__ __launch_bounds__(256) void gemm_nt(const bf16* __restrict__ A,
                                               const bf16* __restrict__ BT,
                                               bf16* __restrict__ Cb,
                                               float* __restrict__ Cf, int act) {
  constexpr int TM = 128, TN = 128, BK = 32, LDT = BK + 8;  // 40 elems = 80B
  __shared__ bf16 Al[TM * LDT];
  __shared__ bf16 Bl[TN * LDT];
  const int tid = threadIdx.x;
  const int wave = tid >> 6, lane = tid & 63;
  const int quad = lane >> 4, l16 = lane & 15;
  const int bm = blockIdx.x * TM, bn = blockIdx.y * TN;
  const int wm = (wave & 1) * 64, wn = (wave >> 1) * 64;
  const int sr = tid >> 1, scol = (tid & 1) * 16;

  v4f zero = {0.f, 0.f, 0.f, 0.f};
  v4f acc[4][4];
#pragma unroll
  for (int i = 0; i < 4; i++)
#pragma unroll
    for (int j = 0; j < 4; j++) acc[i][j] = zero;

  const bf16* ga = A + (size_t)(bm + sr) * D_ + scol;
  const bf16* gb = BT + (size_t)(bn + sr) * D_ + scol;

  for (int k0 = 0; k0 < D_; k0 += BK) {
    bf16x8 a0 = *(const bf16x8*)(ga + k0);
    bf16x8 a1 = *(const bf16x8*)(ga + k0 + 8);
    bf16x8 b0 = *(const bf16x8*)(gb + k0);
    bf16x8 b1 = *(const bf16x8*)(gb + k0 + 8);
    __syncthreads();
    *(bf16x8*)&Al[sr * LDT + scol] = a0;
    *(bf16x8*)&Al[sr * LDT + scol + 8] = a1;
    *(bf16x8*)&Bl[sr * LDT + scol] = b0;
    *(bf16x8*)&Bl[sr * LDT + scol + 8] = b1;
    __syncthreads();
    bf16x8 af[4], bfr[4];
#pragma unroll
    for (int i = 0; i < 4; i++)
      af[i] = *(const bf16x8*)&Al[(wm + i * 16 + l16) * LDT + quad * 8];
#pragma unroll
    for (int j = 0; j < 4; j++)
      bfr[j] = *(const bf16x8*)&Bl[(wn + j * 16 + l16) * LDT + quad * 8];
#pragma unroll
    for (int i = 0; i < 4; i++)
#pragma unroll
      for (int j = 0; j < 4; j++) acc[i][j] = MFMA16(af[i], bfr[j], acc[i][j]);
  }
#pragma unroll
  for (int i = 0; i < 4; i++)
#pragma unroll
    for (int j = 0; j < 4; j++) {
      const int row0 = bm + wm + i * 16 + quad * 4;
      const int col = bn + wn + j * 16 + l16;
#pragma unroll
      for (int r = 0; r < 4; r++) {
        float x = acc[i][j][r];
        if (act) x = x > 0.f ? x + 1.f : __expf(x);
        if (Cf) Cf[(size_t)(row0 + r) * D_ + col] = x;
        else    Cb[(size_t)(row0 + r) * D_ + col] = (bf16)x;
      }
    }
}

// ---------------------------------------------------------------------------
// Pass 1: per-chunk KV outer-product sums + k-sums (fp32).
// grid (NC, BH).  states[bh][c][d*64+e] = sum_t k[t][d]*v[t][e];  [4096+d]=sum k
// ---------------------------------------------------------------------------
__global__ __launch_bounds__(256) void chunk_kv(const bf16* __restrict__ kb,
                                                const bf16* __restrict__ vb,
                                                float* __restrict__ states) {
  constexpr int LD = 88;  // padded row stride (176B, 16B-aligned)
  __shared__ bf16 Kl[CHUNK * LD];
  __shared__ bf16 Vl[CHUNK * LD];
  const int tid = threadIdx.x;
  const int c = blockIdx.x, bh = blockIdx.y;
  const int b = bh >> 4, h = bh & 15;
  const size_t gbase = ((size_t)(b * S_ + c * CHUNK)) * D_ + h * DH;
#pragma unroll
  for (int rep = 0; rep < 2; rep++) {
    int flat = tid + rep * 256;
    int r = flat >> 3, sg = (flat & 7) * 8;
    *(bf16x8*)&Kl[r * LD + sg] = *(const bf16x8*)(kb + gbase + (size_t)r * D_ + sg);
    *(bf16x8*)&Vl[r * LD + sg] = *(const bf16x8*)(vb + gbase + (size_t)r * D_ + sg);
  }
  __syncthreads();
  const int d0 = (tid >> 4) * 4, e0 = (tid & 15) * 4;
  float acc[4][4] = {};
  for (int t = 0; t < CHUNK; t++) {
    bf16x4 k4 = *(const bf16x4*)&Kl[t * LD + d0];
    bf16x4 v4 = *(const bf16x4*)&Vl[t * LD + e0];
    float kf[4], vf[4];
#pragma unroll
    for (int i = 0; i < 4; i++) { kf[i] = (float)k4[i]; vf[i] = (float)v4[i]; }
#pragma unroll
    for (int i = 0; i < 4; i++)
#pragma unroll
      for (int j = 0; j < 4; j++) acc[i][j] += kf[i] * vf[j];
  }
  float* out = states + ((size_t)bh * NC + c) * STATE_N;
#pragma unroll
  for (int i = 0; i < 4; i++)
#pragma unroll
    for (int j = 0; j < 4; j++) out[(d0 + i) * 64 + (e0 + j)] = acc[i][j];
  if (tid < 64) {
    float zs = 0.f;
    for (int t = 0; t < CHUNK; t++) zs += (float)Kl[t * LD + tid];
    out[4096 + tid] = zs;
  }
}

// ---------------------------------------------------------------------------
// Exclusive prefix over chunks + state_cache init (fp32 input).
// grid (BH, 17) x 256.  After: states[bh][c] = state at START of chunk c.
// ---------------------------------------------------------------------------
__global__ __launch_bounds__(256) void state_prefix(const float* __restrict__ sc,
                                                    float* __restrict__ states) {
  const int bh = blockIdx.x;
  const int e = blockIdx.y * 256 + threadIdx.x;
  if (e >= STATE_N) return;
  const float* scb = sc + (size_t)bh * (DH + 1) * DH;
  // S0 flat (d*64+e) coincides with the (DH+1,DH) row-major layout; z at row DH.
  float run = scb[e];
  float* p = states + (size_t)bh * NC * STATE_N + e;
  for (int c = 0; c < NC; c++) {
    float tmp = p[(size_t)c * STATE_N];
    p[(size_t)c * STATE_N] = run;
    run += tmp;
  }
}

// ---------------------------------------------------------------------------
// Pass 2: per chunk, P = mask(Q K^T) (incl. diagonal), num = P@V + Q@S0,
// den = rowsum(P) + Q.z0, out = num/(den+eps).  grid (NC, BH) x 256 (4 waves).
// Wave w owns output rows [w*16, w*16+16).
// ---------------------------------------------------------------------------
__global__ __launch_bounds__(256) void attn_pass2(
    const bf16* __restrict__ qb, const bf16* __restrict__ kb,
    const bf16* __restrict__ vb, const float* __restrict__ states,
    bf16* __restrict__ ao) {
  constexpr int LD = 88;
  __shared__ bf16 Ql[CHUNK * LD];
  __shared__ bf16 Kl[CHUNK * LD];
  __shared__ bf16 VT[DH * LD];    // VT[e][j] = V[j][e]
  __shared__ bf16 S0T[DH * LD];   // S0T[e][d] = S0[d][e]
  __shared__ bf16 Pl[CHUNK * LD]; // masked P, row-major [t][j]
  __shared__ float denl[CHUNK];
  __shared__ float z0l[DH];
  const int tid = threadIdx.x;
  const int wave = tid >> 6, lane = tid & 63;
  const int quad = lane >> 4, l16 = lane & 15;
  const int c = blockIdx.x, bh = blockIdx.y;
  const int b = bh >> 4, h = bh & 15;
  const size_t gbase = ((size_t)(b * S_ + c * CHUNK)) * D_ + h * DH;

#pragma unroll
  for (int rep = 0; rep < 2; rep++) {
    int flat = tid + rep * 256;
    int r = flat >> 3, sg = (flat & 7) * 8;
    *(bf16x8*)&Ql[r * LD + sg] = *(const bf16x8*)(qb + gbase + (size_t)r * D_ + sg);
    *(bf16x8*)&Kl[r * LD + sg] = *(const bf16x8*)(kb + gbase + (size_t)r * D_ + sg);
    bf16x8 vv = *(const bf16x8*)(vb + gbase + (size_t)r * D_ + sg);
#pragma unroll
    for (int u = 0; u < 8; u++) VT[(sg + u) * LD + r] = vv[u];
  }
  const float* st = states + ((size_t)bh * NC + c) * STATE_N;
  for (int f = tid; f < 4096; f += 256) S0T[(f & 63) * LD + (f >> 6)] = (bf16)st[f];
  if (tid < DH) z0l[tid] = st[4096 + tid];
  __syncthreads();

  // phase 1: P = Q K^T  (rows wave*16..+16, cols 0..63, Kdim = DH = 64)
  v4f zero = {0.f, 0.f, 0.f, 0.f};
  v4f pacc[4];
#pragma unroll
  for (int j = 0; j < 4; j++) pacc[j] = zero;
#pragma unroll
  for (int ks = 0; ks < 2; ks++) {
    bf16x8 aq = *(const bf16x8*)&Ql[(wave * 16 + l16) * LD + ks * 32 + quad * 8];
#pragma unroll
    for (int j = 0; j < 4; j++) {
      bf16x8 bk = *(const bf16x8*)&Kl[(j * 16 + l16) * LD + ks * 32 + quad * 8];
      pacc[j] = MFMA16(aq, bk, pacc[j]);
    }
  }
  // mask (keep col <= t), stash to LDS, per-row sums
  float rs[4] = {0.f, 0.f, 0.f, 0.f};
#pragma unroll
  for (int j = 0; j < 4; j++) {
#pragma unroll
    for (int r = 0; r < 4; r++) {
      int t = wave * 16 + quad * 4 + r;
      int col = j * 16 + l16;
      float p = (col <= t) ? pacc[j][r] : 0.f;
      Pl[t * LD + col] = (bf16)p;
      rs[r] += p;
    }
  }
#pragma unroll
  for (int m = 1; m < 16; m <<= 1)
#pragma unroll
    for (int r = 0; r < 4; r++) rs[r] += __shfl_xor(rs[r], m, 64);
  if (l16 == 0)
#pragma unroll
    for (int r = 0; r < 4; r++) denl[wave * 16 + quad * 4 + r] = rs[r];
  __syncthreads();
  if (tid < CHUNK) {
    float qz = 0.f;
    for (int d = 0; d < DH; d++) qz += (float)Ql[tid * LD + d] * z0l[d];
    denl[tid] += qz;
  }
  __syncthreads();

  // phase 2: num = P@V + Q@S0
  v4f nacc[4];
#pragma unroll
  for (int j = 0; j < 4; j++) nacc[j] = zero;
#pragma unroll
  for (int ks = 0; ks < 2; ks++) {
    bf16x8 ap = *(const bf16x8*)&Pl[(wave * 16 + l16) * LD + ks * 32 + quad * 8];
#pragma unroll
    for (int j = 0; j < 4; j++) {
      bf16x8 bv = *(const bf16x8*)&VT[(j * 16 + l16) * LD + ks * 32 + quad * 8];
      nacc[j] = MFMA16(ap, bv, nacc[j]);
    }
  }
#pragma unroll
  for (int ks = 0; ks < 2; ks++) {
    bf16x8 aq = *(const bf16x8*)&Ql[(wave * 16 + l16) * LD + ks * 32 + quad * 8];
#pragma unroll
    for (int j = 0; j < 4; j++) {
      bf16x8 bs = *(const bf16x8*)&S0T[(j * 16 + l16) * LD + ks * 32 + quad * 8];
      nacc[j] = MFMA16(aq, bs, nacc[j]);
    }
  }
#pragma unroll
  for (int j = 0; j < 4; j++) {
#pragma unroll
    for (int r = 0; r < 4; r++) {
      int t = wave * 16 + quad * 4 + r;
      int e = j * 16 + l16;
      float o = nacc[j][r] / (denl[t] + EPS);
      ao[gbase + (size_t)t * D_ + e] = (bf16)o;
    }
  }
}

// ---------------------------------------------------------------------------
extern "C" void kernel_launch(void* const* d_in, const int* in_sizes, int n_in,
                              void* d_out, int out_size, void* d_ws, size_t ws_size,
                              hipStream_t stream) {
  const float* x  = (const float*)d_in[0];
  const float* sc = (const float*)d_in[1];
  const float* Wq = (const float*)d_in[2];
  const float* Wk = (const float*)d_in[3];
  const float* Wv = (const float*)d_in[4];
  const float* Wo = (const float*)d_in[5];
  float* out = (float*)d_out;

  const size_t MSZ = (size_t)B_ * S_ * D_;  // 16,777,216 elems
  const size_t WSZ = (size_t)D_ * D_;       // 1,048,576 elems
  bf16* xb = (bf16*)d_ws;
  bf16* qb = xb + MSZ;
  bf16* kb = qb + MSZ;
  bf16* vb = kb + MSZ;
  bf16* ao = vb + MSZ;
  bf16* wt = ao + MSZ;  // 4 transposed bf16 weight matrices
  float* states = (float*)(wt + 4 * WSZ);  // BH*NC*4160 fp32 (~68 MB)

  cvt_f32_bf16<<<MSZ / (256 * 8), 256, 0, stream>>>(x, xb);
  dim3 tgrid(32, 32);
  transpose_w<<<tgrid, 256, 0, stream>>>(Wq, wt + 0 * WSZ);
  transpose_w<<<tgrid, 256, 0, stream>>>(Wk, wt + 1 * WSZ);
  transpose_w<<<tgrid, 256, 0, stream>>>(Wv, wt + 2 * WSZ);
  transpose_w<<<tgrid, 256, 0, stream>>>(Wo, wt + 3 * WSZ);

  dim3 ggrid(128, 8);
  gemm_nt<<<ggrid, 256, 0, stream>>>(xb, wt + 0 * WSZ, qb, nullptr, 1);
  gemm_nt<<<ggrid, 256, 0, stream>>>(xb, wt + 1 * WSZ, kb, nullptr, 1);
  gemm_nt<<<ggrid, 256, 0, stream>>>(xb, wt + 2 * WSZ, vb, nullptr, 0);

  chunk_kv<<<dim3(NC, BH), 256, 0, stream>>>(kb, vb, states);
  state_prefix<<<dim3(BH, 17), 256, 0, stream>>>(sc, states);
  attn_pass2<<<dim3(NC, BH), 256, 0, stream>>>(qb, kb, vb, states, ao);

  gemm_nt<<<ggrid, 256, 0, stream>>>(ao, wt + 3 * WSZ, nullptr, out, 0);
}

// Round 3
// 477.577 us; speedup vs baseline: 1.0394x; 1.0394x over previous
//
#include <hip/hip_runtime.h>

#define B_ 4
#define S_ 4096
#define D_ 1024
#define H_ 16
#define DH 64
#define CHUNK 64
#define NC (S_ / CHUNK)   // 64 chunks
#define BH (B_ * H_)      // 64 (b,h) sequences
#define STATE_N 4160      // 64*64 S entries + 64 z entries
#define EPS 1e-6f

typedef __bf16 bf16;
typedef __bf16 bf16x8 __attribute__((ext_vector_type(8)));
typedef __bf16 bf16x4 __attribute__((ext_vector_type(4)));
typedef float v4f __attribute__((ext_vector_type(4)));

#define MFMA16(a, b, c) __builtin_amdgcn_mfma_f32_16x16x32_bf16(a, b, c, 0, 0, 0)

// async global->LDS, 16B per lane; LDS dest = wave-uniform base + lane*16
__device__ __forceinline__ void load_lds16(const bf16* g, bf16* l) {
  __builtin_amdgcn_global_load_lds(
      (const __attribute__((address_space(1))) unsigned int*)g,
      (__attribute__((address_space(3))) unsigned int*)l, 16, 0, 0);
}

// ---------------------------------------------------------------------------
// fp32 -> bf16 convert (x): 8 elems/thread, vectorized.
// ---------------------------------------------------------------------------
__global__ __launch_bounds__(256) void cvt_f32_bf16(const float* __restrict__ in,
                                                    bf16* __restrict__ out) {
  const size_t i = ((size_t)blockIdx.x * 256 + threadIdx.x) * 8;
  float4 a = *(const float4*)(in + i);
  float4 b = *(const float4*)(in + i + 4);
  bf16x8 o;
  o[0] = (bf16)a.x; o[1] = (bf16)a.y; o[2] = (bf16)a.z; o[3] = (bf16)a.w;
  o[4] = (bf16)b.x; o[5] = (bf16)b.y; o[6] = (bf16)b.z; o[7] = (bf16)b.w;
  *(bf16x8*)(out + i) = o;
}

// ---------------------------------------------------------------------------
// Fused weight transpose + fp32->bf16 for all 4 weights (z selects matrix).
// out[z][n*1024+k] = (bf16)W_z[k*1024+n]
// ---------------------------------------------------------------------------
__global__ __launch_bounds__(256) void transpose_w4(
    const float* __restrict__ w0, const float* __restrict__ w1,
    const float* __restrict__ w2, const float* __restrict__ w3,
    bf16* __restrict__ out) {
  __shared__ float tile[32][33];
  const int z = blockIdx.z;
  const float* in = (z == 0) ? w0 : (z == 1) ? w1 : (z == 2) ? w2 : w3;
  bf16* o = out + (size_t)z * D_ * D_;
  const int bx = blockIdx.x * 32, by = blockIdx.y * 32;
  const int tx = threadIdx.x & 31, ty = threadIdx.x >> 5;  // 32 x 8
#pragma unroll
  for (int i = 0; i < 32; i += 8)
    tile[ty + i][tx] = in[(size_t)(by + ty + i) * D_ + bx + tx];
  __syncthreads();
#pragma unroll
  for (int i = 0; i < 32; i += 8)
    o[(size_t)(bx + ty + i) * D_ + by + tx] = (bf16)tile[tx][ty + i];
}

// ---------------------------------------------------------------------------
// NT GEMM: C[M,N] = act(A[M,K] @ BT[N,K]^T), M=16384, N=K=1024, bf16 in,
// fp32 accum.  act=1 applies phi(x)=elu(x)+1.  Output: bf16 (Cb) unless
// Cf != nullptr (fp32).
// m97 structure: 128x128 tile, BK=32, global_load_lds width=16 staging
// (unpadded 64B rows), 16 MFMA / k-step / wave, LDS-staged coalesced epilogue.
// ---------------------------------------------------------------------------
__global__ __launch_bounds__(256) void gemm_nt(const bf16* __restrict__ A,
                                               const bf16* __restrict__ BT,
                                               bf16* __restrict__ Cb,
                                               float* __restrict__ Cf, int act) {
  constexpr int TM = 128, TN = 128, BK = 32;
  constexpr int CLD = 132;  // epilogue fp32 row stride
  __shared__ __align__(16) char smem[32 * CLD * 4];  // 16896B >= 16KB staging
  bf16* Al = (bf16*)smem;                 // [128][32] bf16, 8KB
  bf16* Bl = (bf16*)(smem + 8192);        // [128][32] bf16, 8KB
  float* Cl = (float*)smem;               // epilogue [32][132] fp32

  const int tid = threadIdx.x;
  const int wave = tid >> 6, lane = tid & 63;
  const int quad = lane >> 4, l16 = lane & 15;
  const int bm = blockIdx.x * TM, bn = blockIdx.y * TN;
  const int wm = (wave & 1) * 64, wn = (wave >> 1) * 64;

  // staging: wave w covers tile rows [w*16, w*16+16) (call adds +64 rows);
  // lane -> row w*16 + lane/4, 16B group lane%4  (matches HW lane*16 fill)
  const int srow = wave * 16 + (lane >> 2);
  const int sgrp = lane & 3;
  const bf16* gA0 = A + (size_t)(bm + srow) * D_ + sgrp * 8;
  const bf16* gA1 = gA0 + (size_t)64 * D_;
  const bf16* gB0 = BT + (size_t)(bn + srow) * D_ + sgrp * 8;
  const bf16* gB1 = gB0 + (size_t)64 * D_;
  bf16* lA0 = Al + wave * 16 * BK;  // wave-uniform bases
  bf16* lA1 = lA0 + 64 * BK;
  bf16* lB0 = Bl + wave * 16 * BK;
  bf16* lB1 = lB0 + 64 * BK;

  v4f zero = {0.f, 0.f, 0.f, 0.f};
  v4f acc[4][4];
#pragma unroll
  for (int i = 0; i < 4; i++)
#pragma unroll
    for (int j = 0; j < 4; j++) acc[i][j] = zero;

  for (int k0 = 0; k0 < D_; k0 += BK) {
    __syncthreads();  // prior iter's LDS reads complete
    load_lds16(gA0 + k0, lA0);
    load_lds16(gA1 + k0, lA1);
    load_lds16(gB0 + k0, lB0);
    load_lds16(gB1 + k0, lB1);
    __syncthreads();  // drains vmcnt -> staging visible
    bf16x8 af[4], bfr[4];
#pragma unroll
    for (int i = 0; i < 4; i++)
      af[i] = *(const bf16x8*)&Al[(wm + i * 16 + l16) * BK + quad * 8];
#pragma unroll
    for (int j = 0; j < 4; j++)
      bfr[j] = *(const bf16x8*)&Bl[(wn + j * 16 + l16) * BK + quad * 8];
#pragma unroll
    for (int i = 0; i < 4; i++)
#pragma unroll
      for (int j = 0; j < 4; j++) acc[i][j] = MFMA16(af[i], bfr[j], acc[i][j]);
  }

  // ---- coalesced epilogue through LDS (fixes partial-line write amp) ----
  const int lr = (wave & 1) * 16 + quad * 4;  // local row base in Cl
  const int rrow = tid >> 3;                   // readback: local row 0..31
  const int rseg = (tid & 7) * 16;             // readback: col seg (16 floats)
  const int grow = bm + (rrow >> 4) * 64 + (rrow & 15);  // + i*16 below
#pragma unroll
  for (int i = 0; i < 4; i++) {
    __syncthreads();  // k-loop reads done (i=0) / prior readback done (i>0)
#pragma unroll
    for (int j = 0; j < 4; j++) {
      const int col = wn + j * 16 + l16;
#pragma unroll
      for (int r = 0; r < 4; r++) {
        float x = acc[i][j][r];
        if (act) x = x > 0.f ? x + 1.f : __expf(x);
        Cl[(lr + r) * CLD + col] = x;
      }
    }
    __syncthreads();
    const float* src = &Cl[rrow * CLD + rseg];
    if (Cf) {
      float* dst = Cf + (size_t)(grow + i * 16) * D_ + bn + rseg;
#pragma unroll
      for (int u = 0; u < 4; u++)
        *(float4*)(dst + u * 4) = *(const float4*)(src + u * 4);
    } else {
      bf16x8 o0, o1;
#pragma unroll
      for (int u = 0; u < 8; u++) { o0[u] = (bf16)src[u]; o1[u] = (bf16)src[8 + u]; }
      bf16* dst = Cb + (size_t)(grow + i * 16) * D_ + bn + rseg;
      *(bf16x8*)dst = o0;
      *(bf16x8*)(dst + 8) = o1;
    }
  }
}

// ---------------------------------------------------------------------------
// Pass 1: per-chunk KV outer-product sums + k-sums (fp32).
// grid (NC, BH).  states[bh][c][d*64+e] = sum_t k[t][d]*v[t][e];  [4096+d]=sum k
// ---------------------------------------------------------------------------
__global__ __launch_bounds__(256) void chunk_kv(const bf16* __restrict__ kb,
                                                const bf16* __restrict__ vb,
                                                float* __restrict__ states) {
  constexpr int LD = 88;
  __shared__ bf16 Kl[CHUNK * LD];
  __shared__ bf16 Vl[CHUNK * LD];
  const int tid = threadIdx.x;
  const int c = blockIdx.x, bh = blockIdx.y;
  const int b = bh >> 4, h = bh & 15;
  const size_t gbase = ((size_t)(b * S_ + c * CHUNK)) * D_ + h * DH;
#pragma unroll
  for (int rep = 0; rep < 2; rep++) {
    int flat = tid + rep * 256;
    int r = flat >> 3, sg = (flat & 7) * 8;
    *(bf16x8*)&Kl[r * LD + sg] = *(const bf16x8*)(kb + gbase + (size_t)r * D_ + sg);
    *(bf16x8*)&Vl[r * LD + sg] = *(const bf16x8*)(vb + gbase + (size_t)r * D_ + sg);
  }
  __syncthreads();
  const int d0 = (tid >> 4) * 4, e0 = (tid & 15) * 4;
  float acc[4][4] = {};
  for (int t = 0; t < CHUNK; t++) {
    bf16x4 k4 = *(const bf16x4*)&Kl[t * LD + d0];
    bf16x4 v4 = *(const bf16x4*)&Vl[t * LD + e0];
    float kf[4], vf[4];
#pragma unroll
    for (int i = 0; i < 4; i++) { kf[i] = (float)k4[i]; vf[i] = (float)v4[i]; }
#pragma unroll
    for (int i = 0; i < 4; i++)
#pragma unroll
      for (int j = 0; j < 4; j++) acc[i][j] += kf[i] * vf[j];
  }
  float* out = states + ((size_t)bh * NC + c) * STATE_N;
#pragma unroll
  for (int i = 0; i < 4; i++)
#pragma unroll
    for (int j = 0; j < 4; j++) out[(d0 + i) * 64 + (e0 + j)] = acc[i][j];
  if (tid < 64) {
    float zs = 0.f;
    for (int t = 0; t < CHUNK; t++) zs += (float)Kl[t * LD + tid];
    out[4096 + tid] = zs;
  }
}

// ---------------------------------------------------------------------------
// Exclusive prefix over chunks + state_cache init (fp32 input).
// grid (BH, 17) x 256.  After: states[bh][c] = state at START of chunk c.
// ---------------------------------------------------------------------------
__global__ __launch_bounds__(256) void state_prefix(const float* __restrict__ sc,
                                                    float* __restrict__ states) {
  const int bh = blockIdx.x;
  const int e = blockIdx.y * 256 + threadIdx.x;
  if (e >= STATE_N) return;
  const float* scb = sc + (size_t)bh * (DH + 1) * DH;
  float run = scb[e];
  float* p = states + (size_t)bh * NC * STATE_N + e;
  for (int c = 0; c < NC; c++) {
    float tmp = p[(size_t)c * STATE_N];
    p[(size_t)c * STATE_N] = run;
    run += tmp;
  }
}

// ---------------------------------------------------------------------------
// Pass 2: per chunk, P = mask(Q K^T) (incl. diagonal), num = P@V + Q@S0,
// den = rowsum(P) + Q.z0, out = num/(den+eps).  grid (NC, BH) x 256 (4 waves).
// ---------------------------------------------------------------------------
__global__ __launch_bounds__(256) void attn_pass2(
    const bf16* __restrict__ qb, const bf16* __restrict__ kb,
    const bf16* __restrict__ vb, const float* __restrict__ states,
    bf16* __restrict__ ao) {
  constexpr int LD = 88;
  __shared__ bf16 Ql[CHUNK * LD];
  __shared__ bf16 Kl[CHUNK * LD];
  __shared__ bf16 VT[DH * LD];    // VT[e][j] = V[j][e]
  __shared__ bf16 S0T[DH * LD];   // S0T[e][d] = S0[d][e]
  __shared__ bf16 Pl[CHUNK * LD]; // masked P, row-major [t][j]
  __shared__ float denl[CHUNK];
  __shared__ float z0l[DH];
  const int tid = threadIdx.x;
  const int wave = tid >> 6, lane = tid & 63;
  const int quad = lane >> 4, l16 = lane & 15;
  const int c = blockIdx.x, bh = blockIdx.y;
  const int b = bh >> 4, h = bh & 15;
  const size_t gbase = ((size_t)(b * S_ + c * CHUNK)) * D_ + h * DH;

#pragma unroll
  for (int rep = 0; rep < 2; rep++) {
    int flat = tid + rep * 256;
    int r = flat >> 3, sg = (flat & 7) * 8;
    *(bf16x8*)&Ql[r * LD + sg] = *(const bf16x8*)(qb + gbase + (size_t)r * D_ + sg);
    *(bf16x8*)&Kl[r * LD + sg] = *(const bf16x8*)(kb + gbase + (size_t)r * D_ + sg);
    bf16x8 vv = *(const bf16x8*)(vb + gbase + (size_t)r * D_ + sg);
#pragma unroll
    for (int u = 0; u < 8; u++) VT[(sg + u) * LD + r] = vv[u];
  }
  const float* st = states + ((size_t)bh * NC + c) * STATE_N;
  for (int f = tid; f < 4096; f += 256) S0T[(f & 63) * LD + (f >> 6)] = (bf16)st[f];
  if (tid < DH) z0l[tid] = st[4096 + tid];
  __syncthreads();

  // phase 1: P = Q K^T
  v4f zero = {0.f, 0.f, 0.f, 0.f};
  v4f pacc[4];
#pragma unroll
  for (int j = 0; j < 4; j++) pacc[j] = zero;
#pragma unroll
  for (int ks = 0; ks < 2; ks++) {
    bf16x8 aq = *(const bf16x8*)&Ql[(wave * 16 + l16) * LD + ks * 32 + quad * 8];
#pragma unroll
    for (int j = 0; j < 4; j++) {
      bf16x8 bk = *(const bf16x8*)&Kl[(j * 16 + l16) * LD + ks * 32 + quad * 8];
      pacc[j] = MFMA16(aq, bk, pacc[j]);
    }
  }
  float rs[4] = {0.f, 0.f, 0.f, 0.f};
#pragma unroll
  for (int j = 0; j < 4; j++) {
#pragma unroll
    for (int r = 0; r < 4; r++) {
      int t = wave * 16 + quad * 4 + r;
      int col = j * 16 + l16;
      float p = (col <= t) ? pacc[j][r] : 0.f;
      Pl[t * LD + col] = (bf16)p;
      rs[r] += p;
    }
  }
#pragma unroll
  for (int m = 1; m < 16; m <<= 1)
#pragma unroll
    for (int r = 0; r < 4; r++) rs[r] += __shfl_xor(rs[r], m, 64);
  if (l16 == 0)
#pragma unroll
    for (int r = 0; r < 4; r++) denl[wave * 16 + quad * 4 + r] = rs[r];
  __syncthreads();
  if (tid < CHUNK) {
    float qz = 0.f;
    for (int d = 0; d < DH; d++) qz += (float)Ql[tid * LD + d] * z0l[d];
    denl[tid] += qz;
  }
  __syncthreads();

  // phase 2: num = P@V + Q@S0
  v4f nacc[4];
#pragma unroll
  for (int j = 0; j < 4; j++) nacc[j] = zero;
#pragma unroll
  for (int ks = 0; ks < 2; ks++) {
    bf16x8 ap = *(const bf16x8*)&Pl[(wave * 16 + l16) * LD + ks * 32 + quad * 8];
#pragma unroll
    for (int j = 0; j < 4; j++) {
      bf16x8 bv = *(const bf16x8*)&VT[(j * 16 + l16) * LD + ks * 32 + quad * 8];
      nacc[j] = MFMA16(ap, bv, nacc[j]);
    }
  }
#pragma unroll
  for (int ks = 0; ks < 2; ks++) {
    bf16x8 aq = *(const bf16x8*)&Ql[(wave * 16 + l16) * LD + ks * 32 + quad * 8];
#pragma unroll
    for (int j = 0; j < 4; j++) {
      bf16x8 bs = *(const bf16x8*)&S0T[(j * 16 + l16) * LD + ks * 32 + quad * 8];
      nacc[j] = MFMA16(aq, bs, nacc[j]);
    }
  }
#pragma unroll
  for (int j = 0; j < 4; j++) {
#pragma unroll
    for (int r = 0; r < 4; r++) {
      int t = wave * 16 + quad * 4 + r;
      int e = j * 16 + l16;
      float o = nacc[j][r] / (denl[t] + EPS);
      ao[gbase + (size_t)t * D_ + e] = (bf16)o;
    }
  }
}

// ---------------------------------------------------------------------------
extern "C" void kernel_launch(void* const* d_in, const int* in_sizes, int n_in,
                              void* d_out, int out_size, void* d_ws, size_t ws_size,
                              hipStream_t stream) {
  const float* x  = (const float*)d_in[0];
  const float* sc = (const float*)d_in[1];
  const float* Wq = (const float*)d_in[2];
  const float* Wk = (const float*)d_in[3];
  const float* Wv = (const float*)d_in[4];
  const float* Wo = (const float*)d_in[5];
  float* out = (float*)d_out;

  const size_t MSZ = (size_t)B_ * S_ * D_;  // 16,777,216 elems
  const size_t WSZ = (size_t)D_ * D_;       // 1,048,576 elems
  bf16* xb = (bf16*)d_ws;
  bf16* qb = xb + MSZ;
  bf16* kb = qb + MSZ;
  bf16* vb = kb + MSZ;
  bf16* ao = vb + MSZ;
  bf16* wt = ao + MSZ;  // 4 transposed bf16 weight matrices
  float* states = (float*)(wt + 4 * WSZ);  // BH*NC*4160 fp32 (~68 MB)

  cvt_f32_bf16<<<MSZ / (256 * 8), 256, 0, stream>>>(x, xb);
  transpose_w4<<<dim3(32, 32, 4), 256, 0, stream>>>(Wq, Wk, Wv, Wo, wt);

  dim3 ggrid(128, 8);
  gemm_nt<<<ggrid, 256, 0, stream>>>(xb, wt + 0 * WSZ, qb, nullptr, 1);
  gemm_nt<<<ggrid, 256, 0, stream>>>(xb, wt + 1 * WSZ, kb, nullptr, 1);
  gemm_nt<<<ggrid, 256, 0, stream>>>(xb, wt + 2 * WSZ, vb, nullptr, 0);

  chunk_kv<<<dim3(NC, BH), 256, 0, stream>>>(kb, vb, states);
  state_prefix<<<dim3(BH, 17), 256, 0, stream>>>(sc, states);
  attn_pass2<<<dim3(NC, BH), 256, 0, stream>>>(qb, kb, vb, states, ao);

  gemm_nt<<<ggrid, 256, 0, stream>>>(ao, wt + 3 * WSZ, nullptr, out, 0);
}

// Round 4
// 433.515 us; speedup vs baseline: 1.1450x; 1.1016x over previous
//
#include <hip/hip_runtime.h>

#define B_ 4
#define S_ 4096
#define D_ 1024
#define H_ 16
#define DH 64
#define CHUNK 64
#define NC (S_ / CHUNK)   // 64 chunks
#define BH (B_ * H_)      // 64 (b,h) sequences
#define STATE_N 4160      // 64*64 S entries + 64 z entries
#define EPS 1e-6f

typedef __bf16 bf16;
typedef __bf16 bf16x8 __attribute__((ext_vector_type(8)));
typedef __bf16 bf16x4 __attribute__((ext_vector_type(4)));
typedef float v4f __attribute__((ext_vector_type(4)));

#define MFMA16(a, b, c) __builtin_amdgcn_mfma_f32_16x16x32_bf16(a, b, c, 0, 0, 0)

// async global->LDS, 16B per lane; LDS dest = wave-uniform base + lane*16
__device__ __forceinline__ void load_lds16(const bf16* g, bf16* l) {
  __builtin_amdgcn_global_load_lds(
      (const __attribute__((address_space(1))) unsigned int*)g,
      (__attribute__((address_space(3))) unsigned int*)l, 16, 0, 0);
}

// ---------------------------------------------------------------------------
// fp32 -> bf16 convert (x): 8 elems/thread, vectorized.
// ---------------------------------------------------------------------------
__global__ __launch_bounds__(256) void cvt_f32_bf16(const float* __restrict__ in,
                                                    bf16* __restrict__ out) {
  const size_t i = ((size_t)blockIdx.x * 256 + threadIdx.x) * 8;
  float4 a = *(const float4*)(in + i);
  float4 b = *(const float4*)(in + i + 4);
  bf16x8 o;
  o[0] = (bf16)a.x; o[1] = (bf16)a.y; o[2] = (bf16)a.z; o[3] = (bf16)a.w;
  o[4] = (bf16)b.x; o[5] = (bf16)b.y; o[6] = (bf16)b.z; o[7] = (bf16)b.w;
  *(bf16x8*)(out + i) = o;
}

// ---------------------------------------------------------------------------
// Fused weight transpose + fp32->bf16 for all 4 weights (z selects matrix).
// out[z][n*1024+k] = (bf16)W_z[k*1024+n]
// ---------------------------------------------------------------------------
__global__ __launch_bounds__(256) void transpose_w4(
    const float* __restrict__ w0, const float* __restrict__ w1,
    const float* __restrict__ w2, const float* __restrict__ w3,
    bf16* __restrict__ out) {
  __shared__ float tile[32][33];
  const int z = blockIdx.z;
  const float* in = (z == 0) ? w0 : (z == 1) ? w1 : (z == 2) ? w2 : w3;
  bf16* o = out + (size_t)z * D_ * D_;
  const int bx = blockIdx.x * 32, by = blockIdx.y * 32;
  const int tx = threadIdx.x & 31, ty = threadIdx.x >> 5;  // 32 x 8
#pragma unroll
  for (int i = 0; i < 32; i += 8)
    tile[ty + i][tx] = in[(size_t)(by + ty + i) * D_ + bx + tx];
  __syncthreads();
#pragma unroll
  for (int i = 0; i < 32; i += 8)
    o[(size_t)(bx + ty + i) * D_ + by + tx] = (bf16)tile[tx][ty + i];
}

// ---------------------------------------------------------------------------
// NT GEMM with double-buffered global_load_lds prefetch.
// C[M, Nall] = act(A[M,K] @ BT_all^T); BT_all rows indexed by blockIdx.y*128.
// Output matrix z = blockIdx.y>>3 (o0/o1/o2, bf16, act=phi for z<2) unless
// of != nullptr (single fp32 output, z==0, no act).
// Tile 128x128, BK=32, 2-deep LDS pipeline (32KB), LDS-staged epilogue.
// ---------------------------------------------------------------------------
__global__ __launch_bounds__(256) void gemm_nt(const bf16* __restrict__ A,
                                               const bf16* __restrict__ BT,
                                               bf16* __restrict__ o0,
                                               bf16* __restrict__ o1,
                                               bf16* __restrict__ o2,
                                               float* __restrict__ of) {
  constexpr int TM = 128, BK = 32;
  constexpr int CLD = 132;  // epilogue fp32 row stride
  __shared__ __align__(16) char smem[32768];  // 2 x (A 8KB + B 8KB); epilogue reuse
  float* Cl = (float*)smem;  // [32][132] fp32 (16896B)

  const int tid = threadIdx.x;
  const int wave = tid >> 6, lane = tid & 63;
  const int quad = lane >> 4, l16 = lane & 15;
  const int bm = blockIdx.x * TM;
  const int zz = blockIdx.y >> 3;
  const int colg = (blockIdx.y & 7) * 128;  // global col base of this tile
  const int wm = (wave & 1) * 64, wn = (wave >> 1) * 64;
  const int act = (of == nullptr) && (zz < 2);
  bf16* ob = (zz == 0) ? o0 : (zz == 1) ? o1 : o2;

  // staging addressing: lane -> row wave*16 + lane/4 (+64 for 2nd call),
  // 16B seg lane%4; HW fills lds_base + lane*16 (row-major [16][32] per call)
  const int srow = wave * 16 + (lane >> 2);
  const int sgrp = lane & 3;
  const bf16* gA0 = A + (size_t)(bm + srow) * D_ + sgrp * 8;
  const bf16* gA1 = gA0 + (size_t)64 * D_;
  const bf16* gB0 = BT + ((size_t)blockIdx.y * 128 + srow) * D_ + sgrp * 8;
  const bf16* gB1 = gB0 + (size_t)64 * D_;

  v4f zero = {0.f, 0.f, 0.f, 0.f};
  v4f acc[4][4];
#pragma unroll
  for (int i = 0; i < 4; i++)
#pragma unroll
    for (int j = 0; j < 4; j++) acc[i][j] = zero;

  // issue 4 staging DMAs for k-step `ks` into pipeline slot `s`
  auto stage = [&](int ks, int s) {
    bf16* As = (bf16*)(smem + s * 16384);
    bf16* Bs = As + 4096;
    const int ko = ks * BK;
    load_lds16(gA0 + ko, As + wave * 16 * BK);
    load_lds16(gA1 + ko, As + (64 + wave * 16) * BK);
    load_lds16(gB0 + ko, Bs + wave * 16 * BK);
    load_lds16(gB1 + ko, Bs + (64 + wave * 16) * BK);
  };
  auto compute = [&](int s) {
    const bf16* As = (const bf16*)(smem + s * 16384);
    const bf16* Bs = As + 4096;
    bf16x8 af[4], bfr[4];
#pragma unroll
    for (int i = 0; i < 4; i++)
      af[i] = *(const bf16x8*)&As[(wm + i * 16 + l16) * BK + quad * 8];
#pragma unroll
    for (int j = 0; j < 4; j++)
      bfr[j] = *(const bf16x8*)&Bs[(wn + j * 16 + l16) * BK + quad * 8];
#pragma unroll
    for (int i = 0; i < 4; i++)
#pragma unroll
      for (int j = 0; j < 4; j++) acc[i][j] = MFMA16(af[i], bfr[j], acc[i][j]);
  };

  constexpr int NK = D_ / BK;  // 32
  stage(0, 0);
  __syncthreads();  // slot 0 staged
  for (int k = 0; k < NK; k += 2) {
    if (k + 1 < NK) stage(k + 1, 1);  // in flight during compute(0)
    compute(0);
    __syncthreads();  // drains k+1 loads; slot-0 reads done
    if (k + 2 < NK) stage(k + 2, 0);
    compute(1);
    __syncthreads();
  }

  // ---- coalesced epilogue through LDS ----
  const int lr = (wave & 1) * 16 + quad * 4;
  const int rrow = tid >> 3;
  const int rseg = (tid & 7) * 16;
  const int grow = bm + (rrow >> 4) * 64 + (rrow & 15);
#pragma unroll
  for (int i = 0; i < 4; i++) {
    __syncthreads();
#pragma unroll
    for (int j = 0; j < 4; j++) {
      const int col = wn + j * 16 + l16;
#pragma unroll
      for (int r = 0; r < 4; r++) {
        float x = acc[i][j][r];
        if (act) x = x > 0.f ? x + 1.f : __expf(x);
        Cl[(lr + r) * CLD + col] = x;
      }
    }
    __syncthreads();
    const float* src = &Cl[rrow * CLD + rseg];
    if (of) {
      float* dst = of + (size_t)(grow + i * 16) * D_ + colg + rseg;
#pragma unroll
      for (int u = 0; u < 4; u++)
        *(float4*)(dst + u * 4) = *(const float4*)(src + u * 4);
    } else {
      bf16x8 q0, q1;
#pragma unroll
      for (int u = 0; u < 8; u++) { q0[u] = (bf16)src[u]; q1[u] = (bf16)src[8 + u]; }
      bf16* dst = ob + (size_t)(grow + i * 16) * D_ + colg + rseg;
      *(bf16x8*)dst = q0;
      *(bf16x8*)(dst + 8) = q1;
    }
  }
}

// ---------------------------------------------------------------------------
// Pass 1: per-chunk KV outer-product sums + k-sums (fp32).
// grid (NC, BH).  states[bh][c][d*64+e] = sum_t k[t][d]*v[t][e];  [4096+d]=sum k
// ---------------------------------------------------------------------------
__global__ __launch_bounds__(256) void chunk_kv(const bf16* __restrict__ kb,
                                                const bf16* __restrict__ vb,
                                                float* __restrict__ states) {
  constexpr int LD = 88;
  __shared__ bf16 Kl[CHUNK * LD];
  __shared__ bf16 Vl[CHUNK * LD];
  const int tid = threadIdx.x;
  const int c = blockIdx.x, bh = blockIdx.y;
  const int b = bh >> 4, h = bh & 15;
  const size_t gbase = ((size_t)(b * S_ + c * CHUNK)) * D_ + h * DH;
#pragma unroll
  for (int rep = 0; rep < 2; rep++) {
    int flat = tid + rep * 256;
    int r = flat >> 3, sg = (flat & 7) * 8;
    *(bf16x8*)&Kl[r * LD + sg] = *(const bf16x8*)(kb + gbase + (size_t)r * D_ + sg);
    *(bf16x8*)&Vl[r * LD + sg] = *(const bf16x8*)(vb + gbase + (size_t)r * D_ + sg);
  }
  __syncthreads();
  const int d0 = (tid >> 4) * 4, e0 = (tid & 15) * 4;
  float acc[4][4] = {};
  for (int t = 0; t < CHUNK; t++) {
    bf16x4 k4 = *(const bf16x4*)&Kl[t * LD + d0];
    bf16x4 v4 = *(const bf16x4*)&Vl[t * LD + e0];
    float kf[4], vf[4];
#pragma unroll
    for (int i = 0; i < 4; i++) { kf[i] = (float)k4[i]; vf[i] = (float)v4[i]; }
#pragma unroll
    for (int i = 0; i < 4; i++)
#pragma unroll
      for (int j = 0; j < 4; j++) acc[i][j] += kf[i] * vf[j];
  }
  float* out = states + ((size_t)bh * NC + c) * STATE_N;
#pragma unroll
  for (int i = 0; i < 4; i++)
#pragma unroll
    for (int j = 0; j < 4; j++) out[(d0 + i) * 64 + (e0 + j)] = acc[i][j];
  if (tid < 64) {
    float zs = 0.f;
    for (int t = 0; t < CHUNK; t++) zs += (float)Kl[t * LD + tid];
    out[4096 + tid] = zs;
  }
}

// ---------------------------------------------------------------------------
// Exclusive prefix over chunks + state_cache init (fp32 input).
// grid (BH, 17) x 256.  After: states[bh][c] = state at START of chunk c.
// ---------------------------------------------------------------------------
__global__ __launch_bounds__(256) void state_prefix(const float* __restrict__ sc,
                                                    float* __restrict__ states) {
  const int bh = blockIdx.x;
  const int e = blockIdx.y * 256 + threadIdx.x;
  if (e >= STATE_N) return;
  const float* scb = sc + (size_t)bh * (DH + 1) * DH;
  float run = scb[e];
  float* p = states + (size_t)bh * NC * STATE_N + e;
  for (int c = 0; c < NC; c++) {
    float tmp = p[(size_t)c * STATE_N];
    p[(size_t)c * STATE_N] = run;
    run += tmp;
  }
}

// ---------------------------------------------------------------------------
// Pass 2: per chunk, P = mask(Q K^T) (incl. diagonal), num = P@V + Q@S0,
// den = rowsum(P) + Q.z0, out = num/(den+eps).  grid (NC, BH) x 256 (4 waves).
// ---------------------------------------------------------------------------
__global__ __launch_bounds__(256) void attn_pass2(
    const bf16* __restrict__ qb, const bf16* __restrict__ kb,
    const bf16* __restrict__ vb, const float* __restrict__ states,
    bf16* __restrict__ ao) {
  constexpr int LD = 88;
  __shared__ bf16 Ql[CHUNK * LD];
  __shared__ bf16 Kl[CHUNK * LD];
  __shared__ bf16 VT[DH * LD];    // VT[e][j] = V[j][e]
  __shared__ bf16 S0T[DH * LD];   // S0T[e][d] = S0[d][e]
  __shared__ bf16 Pl[CHUNK * LD]; // masked P, row-major [t][j]
  __shared__ float denl[CHUNK];
  __shared__ float z0l[DH];
  const int tid = threadIdx.x;
  const int wave = tid >> 6, lane = tid & 63;
  const int quad = lane >> 4, l16 = lane & 15;
  const int c = blockIdx.x, bh = blockIdx.y;
  const int b = bh >> 4, h = bh & 15;
  const size_t gbase = ((size_t)(b * S_ + c * CHUNK)) * D_ + h * DH;

#pragma unroll
  for (int rep = 0; rep < 2; rep++) {
    int flat = tid + rep * 256;
    int r = flat >> 3, sg = (flat & 7) * 8;
    *(bf16x8*)&Ql[r * LD + sg] = *(const bf16x8*)(qb + gbase + (size_t)r * D_ + sg);
    *(bf16x8*)&Kl[r * LD + sg] = *(const bf16x8*)(kb + gbase + (size_t)r * D_ + sg);
    bf16x8 vv = *(const bf16x8*)(vb + gbase + (size_t)r * D_ + sg);
#pragma unroll
    for (int u = 0; u < 8; u++) VT[(sg + u) * LD + r] = vv[u];
  }
  const float* st = states + ((size_t)bh * NC + c) * STATE_N;
  for (int f = tid; f < 4096; f += 256) S0T[(f & 63) * LD + (f >> 6)] = (bf16)st[f];
  if (tid < DH) z0l[tid] = st[4096 + tid];
  __syncthreads();

  // phase 1: P = Q K^T
  v4f zero = {0.f, 0.f, 0.f, 0.f};
  v4f pacc[4];
#pragma unroll
  for (int j = 0; j < 4; j++) pacc[j] = zero;
#pragma unroll
  for (int ks = 0; ks < 2; ks++) {
    bf16x8 aq = *(const bf16x8*)&Ql[(wave * 16 + l16) * LD + ks * 32 + quad * 8];
#pragma unroll
    for (int j = 0; j < 4; j++) {
      bf16x8 bk = *(const bf16x8*)&Kl[(j * 16 + l16) * LD + ks * 32 + quad * 8];
      pacc[j] = MFMA16(aq, bk, pacc[j]);
    }
  }
  float rs[4] = {0.f, 0.f, 0.f, 0.f};
#pragma unroll
  for (int j = 0; j < 4; j++) {
#pragma unroll
    for (int r = 0; r < 4; r++) {
      int t = wave * 16 + quad * 4 + r;
      int col = j * 16 + l16;
      float p = (col <= t) ? pacc[j][r] : 0.f;
      Pl[t * LD + col] = (bf16)p;
      rs[r] += p;
    }
  }
#pragma unroll
  for (int m = 1; m < 16; m <<= 1)
#pragma unroll
    for (int r = 0; r < 4; r++) rs[r] += __shfl_xor(rs[r], m, 64);
  if (l16 == 0)
#pragma unroll
    for (int r = 0; r < 4; r++) denl[wave * 16 + quad * 4 + r] = rs[r];
  __syncthreads();
  if (tid < CHUNK) {
    float qz = 0.f;
    for (int d = 0; d < DH; d++) qz += (float)Ql[tid * LD + d] * z0l[d];
    denl[tid] += qz;
  }
  __syncthreads();

  // phase 2: num = P@V + Q@S0
  v4f nacc[4];
#pragma unroll
  for (int j = 0; j < 4; j++) nacc[j] = zero;
#pragma unroll
  for (int ks = 0; ks < 2; ks++) {
    bf16x8 ap = *(const bf16x8*)&Pl[(wave * 16 + l16) * LD + ks * 32 + quad * 8];
#pragma unroll
    for (int j = 0; j < 4; j++) {
      bf16x8 bv = *(const bf16x8*)&VT[(j * 16 + l16) * LD + ks * 32 + quad * 8];
      nacc[j] = MFMA16(ap, bv, nacc[j]);
    }
  }
#pragma unroll
  for (int ks = 0; ks < 2; ks++) {
    bf16x8 aq = *(const bf16x8*)&Ql[(wave * 16 + l16) * LD + ks * 32 + quad * 8];
#pragma unroll
    for (int j = 0; j < 4; j++) {
      bf16x8 bs = *(const bf16x8*)&S0T[(j * 16 + l16) * LD + ks * 32 + quad * 8];
      nacc[j] = MFMA16(aq, bs, nacc[j]);
    }
  }
#pragma unroll
  for (int j = 0; j < 4; j++) {
#pragma unroll
    for (int r = 0; r < 4; r++) {
      int t = wave * 16 + quad * 4 + r;
      int e = j * 16 + l16;
      float o = nacc[j][r] / (denl[t] + EPS);
      ao[gbase + (size_t)t * D_ + e] = (bf16)o;
    }
  }
}

// ---------------------------------------------------------------------------
extern "C" void kernel_launch(void* const* d_in, const int* in_sizes, int n_in,
                              void* d_out, int out_size, void* d_ws, size_t ws_size,
                              hipStream_t stream) {
  const float* x  = (const float*)d_in[0];
  const float* sc = (const float*)d_in[1];
  const float* Wq = (const float*)d_in[2];
  const float* Wk = (const float*)d_in[3];
  const float* Wv = (const float*)d_in[4];
  const float* Wo = (const float*)d_in[5];
  float* out = (float*)d_out;

  const size_t MSZ = (size_t)B_ * S_ * D_;  // 16,777,216 elems
  const size_t WSZ = (size_t)D_ * D_;       // 1,048,576 elems
  bf16* xb = (bf16*)d_ws;
  bf16* qb = xb + MSZ;
  bf16* kb = qb + MSZ;
  bf16* vb = kb + MSZ;
  bf16* ao = vb + MSZ;
  bf16* wt = ao + MSZ;  // 4 transposed bf16 weight matrices [q|k|v|o]
  float* states = (float*)(wt + 4 * WSZ);  // BH*NC*4160 fp32 (~68 MB)

  cvt_f32_bf16<<<MSZ / (256 * 8), 256, 0, stream>>>(x, xb);
  transpose_w4<<<dim3(32, 32, 4), 256, 0, stream>>>(Wq, Wk, Wv, Wo, wt);

  // fused QKV GEMM: BT rows 0..3071 span wt[q|k|v]
  gemm_nt<<<dim3(128, 24), 256, 0, stream>>>(xb, wt, qb, kb, vb, nullptr);

  chunk_kv<<<dim3(NC, BH), 256, 0, stream>>>(kb, vb, states);
  state_prefix<<<dim3(BH, 17), 256, 0, stream>>>(sc, states);
  attn_pass2<<<dim3(NC, BH), 256, 0, stream>>>(qb, kb, vb, states, ao);

  gemm_nt<<<dim3(128, 8), 256, 0, stream>>>(ao, wt + 3 * WSZ, nullptr, nullptr,
                                            nullptr, out);
}

// Round 5
// 427.541 us; speedup vs baseline: 1.1610x; 1.0140x over previous
//
#include <hip/hip_runtime.h>

#define B_ 4
#define S_ 4096
#define D_ 1024
#define H_ 16
#define DH 64
#define CHUNK 64
#define NC (S_ / CHUNK)   // 64 chunks
#define BH (B_ * H_)      // 64 (b,h) sequences
#define STATE_N 4160      // 64*64 S entries + 64 z entries
#define EPS 1e-6f

typedef __bf16 bf16;
typedef __bf16 bf16x8 __attribute__((ext_vector_type(8)));
typedef __bf16 bf16x4 __attribute__((ext_vector_type(4)));
typedef float v4f __attribute__((ext_vector_type(4)));

#define MFMA16(a, b, c) __builtin_amdgcn_mfma_f32_16x16x32_bf16(a, b, c, 0, 0, 0)

// async global->LDS, 16B per lane; LDS dest = wave-uniform base + lane*16
__device__ __forceinline__ void load_lds16(const bf16* g, bf16* l) {
  __builtin_amdgcn_global_load_lds(
      (const __attribute__((address_space(1))) unsigned int*)g,
      (__attribute__((address_space(3))) unsigned int*)l, 16, 0, 0);
}

// ---------------------------------------------------------------------------
// fp32 -> bf16 convert (x): 8 elems/thread, vectorized.
// ---------------------------------------------------------------------------
__global__ __launch_bounds__(256) void cvt_f32_bf16(const float* __restrict__ in,
                                                    bf16* __restrict__ out) {
  const size_t i = ((size_t)blockIdx.x * 256 + threadIdx.x) * 8;
  float4 a = *(const float4*)(in + i);
  float4 b = *(const float4*)(in + i + 4);
  bf16x8 o;
  o[0] = (bf16)a.x; o[1] = (bf16)a.y; o[2] = (bf16)a.z; o[3] = (bf16)a.w;
  o[4] = (bf16)b.x; o[5] = (bf16)b.y; o[6] = (bf16)b.z; o[7] = (bf16)b.w;
  *(bf16x8*)(out + i) = o;
}

// ---------------------------------------------------------------------------
// Fused weight transpose + fp32->bf16 for all 4 weights (z selects matrix).
// out[z][n*1024+k] = (bf16)W_z[k*1024+n]
// ---------------------------------------------------------------------------
__global__ __launch_bounds__(256) void transpose_w4(
    const float* __restrict__ w0, const float* __restrict__ w1,
    const float* __restrict__ w2, const float* __restrict__ w3,
    bf16* __restrict__ out) {
  __shared__ float tile[32][33];
  const int z = blockIdx.z;
  const float* in = (z == 0) ? w0 : (z == 1) ? w1 : (z == 2) ? w2 : w3;
  bf16* o = out + (size_t)z * D_ * D_;
  const int bx = blockIdx.x * 32, by = blockIdx.y * 32;
  const int tx = threadIdx.x & 31, ty = threadIdx.x >> 5;  // 32 x 8
#pragma unroll
  for (int i = 0; i < 32; i += 8)
    tile[ty + i][tx] = in[(size_t)(by + ty + i) * D_ + bx + tx];
  __syncthreads();
#pragma unroll
  for (int i = 0; i < 32; i += 8)
    o[(size_t)(bx + ty + i) * D_ + by + tx] = (bf16)tile[tx][ty + i];
}

// ---------------------------------------------------------------------------
// NT GEMM, double-buffered global_load_lds prefetch, SWIZZLED LDS staging.
// Swizzle: within each 16-row (1KB) staging call, the 16B group g of row r
// is stored at slot r*4 + ((g + (r>>1))&3).  DMA side: lane s loads global
// (row s>>2, group ((s&3)-(s>>2>>1))&3).  Read side: group (quad+(l16>>1))&3.
// -> per-quad bank-groups span all 8, 2-way alias only (free, m136).
// ---------------------------------------------------------------------------
__global__ __launch_bounds__(256) void gemm_nt(const bf16* __restrict__ A,
                                               const bf16* __restrict__ BT,
                                               bf16* __restrict__ o0,
                                               bf16* __restrict__ o1,
                                               bf16* __restrict__ o2,
                                               float* __restrict__ of) {
  constexpr int TM = 128, BK = 32;
  constexpr int CLD = 132;  // epilogue fp32 row stride
  __shared__ __align__(16) char smem[32768];  // 2 x (A 8KB + B 8KB); epilogue reuse
  float* Cl = (float*)smem;  // [32][132] fp32 (16896B)

  const int tid = threadIdx.x;
  const int wave = tid >> 6, lane = tid & 63;
  const int quad = lane >> 4, l16 = lane & 15;
  const int bm = blockIdx.x * TM;
  const int zz = blockIdx.y >> 3;
  const int colg = (blockIdx.y & 7) * 128;  // global col base of this tile
  const int wm = (wave & 1) * 64, wn = (wave >> 1) * 64;
  const int act = (of == nullptr) && (zz < 2);
  bf16* ob = (zz == 0) ? o0 : (zz == 1) ? o1 : o2;

  // staging: lane -> row wave*16 + lane/4 (+64 for 2nd call), swizzled group
  const int srow = wave * 16 + (lane >> 2);
  const int sgrp = ((lane & 3) - ((lane >> 2) >> 1)) & 3;  // swizzle
  const bf16* gA0 = A + (size_t)(bm + srow) * D_ + sgrp * 8;
  const bf16* gA1 = gA0 + (size_t)64 * D_;
  const bf16* gB0 = BT + ((size_t)blockIdx.y * 128 + srow) * D_ + sgrp * 8;
  const bf16* gB1 = gB0 + (size_t)64 * D_;

  // read-side swizzled (loop-invariant) fragment offsets
  int offA[4], offB[4];
#pragma unroll
  for (int i = 0; i < 4; i++) {
    const int pg = (quad + (l16 >> 1)) & 3;  // swizzled group
    offA[i] = (wm + i * 16 + l16) * BK + pg * 8;
    offB[i] = (wn + i * 16 + l16) * BK + pg * 8;
  }

  v4f zero = {0.f, 0.f, 0.f, 0.f};
  v4f acc[4][4];
#pragma unroll
  for (int i = 0; i < 4; i++)
#pragma unroll
    for (int j = 0; j < 4; j++) acc[i][j] = zero;

  auto stage = [&](int ks, int s) {
    bf16* As = (bf16*)(smem + s * 16384);
    bf16* Bs = As + 4096;
    const int ko = ks * BK;
    load_lds16(gA0 + ko, As + wave * 16 * BK);
    load_lds16(gA1 + ko, As + (64 + wave * 16) * BK);
    load_lds16(gB0 + ko, Bs + wave * 16 * BK);
    load_lds16(gB1 + ko, Bs + (64 + wave * 16) * BK);
  };
  auto compute = [&](int s) {
    const bf16* As = (const bf16*)(smem + s * 16384);
    const bf16* Bs = As + 4096;
    bf16x8 af[4], bfr[4];
#pragma unroll
    for (int i = 0; i < 4; i++) af[i] = *(const bf16x8*)&As[offA[i]];
#pragma unroll
    for (int j = 0; j < 4; j++) bfr[j] = *(const bf16x8*)&Bs[offB[j]];
#pragma unroll
    for (int i = 0; i < 4; i++)
#pragma unroll
      for (int j = 0; j < 4; j++) acc[i][j] = MFMA16(af[i], bfr[j], acc[i][j]);
  };

  constexpr int NK = D_ / BK;  // 32
  stage(0, 0);
  __syncthreads();  // slot 0 staged
  for (int k = 0; k < NK; k += 2) {
    if (k + 1 < NK) stage(k + 1, 1);  // in flight during compute(0)
    compute(0);
    __syncthreads();  // drains k+1 loads; slot-0 reads done
    if (k + 2 < NK) stage(k + 2, 0);
    compute(1);
    __syncthreads();
  }

  // ---- coalesced epilogue through LDS ----
  const int lr = (wave & 1) * 16 + quad * 4;
  const int rrow = tid >> 3;
  const int rseg = (tid & 7) * 16;
  const int grow = bm + (rrow >> 4) * 64 + (rrow & 15);
#pragma unroll
  for (int i = 0; i < 4; i++) {
    __syncthreads();
#pragma unroll
    for (int j = 0; j < 4; j++) {
      const int col = wn + j * 16 + l16;
#pragma unroll
      for (int r = 0; r < 4; r++) {
        float x = acc[i][j][r];
        if (act) x = x > 0.f ? x + 1.f : __expf(x);
        Cl[(lr + r) * CLD + col] = x;
      }
    }
    __syncthreads();
    const float* src = &Cl[rrow * CLD + rseg];
    if (of) {
      float* dst = of + (size_t)(grow + i * 16) * D_ + colg + rseg;
#pragma unroll
      for (int u = 0; u < 4; u++)
        *(float4*)(dst + u * 4) = *(const float4*)(src + u * 4);
    } else {
      bf16x8 q0, q1;
#pragma unroll
      for (int u = 0; u < 8; u++) { q0[u] = (bf16)src[u]; q1[u] = (bf16)src[8 + u]; }
      bf16* dst = ob + (size_t)(grow + i * 16) * D_ + colg + rseg;
      *(bf16x8*)dst = q0;
      *(bf16x8*)(dst + 8) = q1;
    }
  }
}

// ---------------------------------------------------------------------------
// Pass 1: per-chunk KV outer-product sums + k-sums (fp32).
// grid (NC, BH).  states[bh][c][d*64+e] = sum_t k[t][d]*v[t][e];  [4096+d]=sum k
// ---------------------------------------------------------------------------
__global__ __launch_bounds__(256) void chunk_kv(const bf16* __restrict__ kb,
                                                const bf16* __restrict__ vb,
                                                float* __restrict__ states) {
  constexpr int LD = 88;
  __shared__ bf16 Kl[CHUNK * LD];
  __shared__ bf16 Vl[CHUNK * LD];
  const int tid = threadIdx.x;
  const int c = blockIdx.x, bh = blockIdx.y;
  const int b = bh >> 4, h = bh & 15;
  const size_t gbase = ((size_t)(b * S_ + c * CHUNK)) * D_ + h * DH;
#pragma unroll
  for (int rep = 0; rep < 2; rep++) {
    int flat = tid + rep * 256;
    int r = flat >> 3, sg = (flat & 7) * 8;
    *(bf16x8*)&Kl[r * LD + sg] = *(const bf16x8*)(kb + gbase + (size_t)r * D_ + sg);
    *(bf16x8*)&Vl[r * LD + sg] = *(const bf16x8*)(vb + gbase + (size_t)r * D_ + sg);
  }
  __syncthreads();
  const int d0 = (tid >> 4) * 4, e0 = (tid & 15) * 4;
  float acc[4][4] = {};
  for (int t = 0; t < CHUNK; t++) {
    bf16x4 k4 = *(const bf16x4*)&Kl[t * LD + d0];
    bf16x4 v4 = *(const bf16x4*)&Vl[t * LD + e0];
    float kf[4], vf[4];
#pragma unroll
    for (int i = 0; i < 4; i++) { kf[i] = (float)k4[i]; vf[i] = (float)v4[i]; }
#pragma unroll
    for (int i = 0; i < 4; i++)
#pragma unroll
      for (int j = 0; j < 4; j++) acc[i][j] += kf[i] * vf[j];
  }
  float* out = states + ((size_t)bh * NC + c) * STATE_N;
#pragma unroll
  for (int i = 0; i < 4; i++)
#pragma unroll
    for (int j = 0; j < 4; j++) out[(d0 + i) * 64 + (e0 + j)] = acc[i][j];
  if (tid < 64) {
    float zs = 0.f;
    for (int t = 0; t < CHUNK; t++) zs += (float)Kl[t * LD + tid];
    out[4096 + tid] = zs;
  }
}

// ---------------------------------------------------------------------------
// Exclusive prefix over chunks + state_cache init (fp32 input).
// grid (BH, 17) x 256.  After: states[bh][c] = state at START of chunk c.
// ---------------------------------------------------------------------------
__global__ __launch_bounds__(256) void state_prefix(const float* __restrict__ sc,
                                                    float* __restrict__ states) {
  const int bh = blockIdx.x;
  const int e = blockIdx.y * 256 + threadIdx.x;
  if (e >= STATE_N) return;
  const float* scb = sc + (size_t)bh * (DH + 1) * DH;
  float run = scb[e];
  float* p = states + (size_t)bh * NC * STATE_N + e;
  for (int c = 0; c < NC; c++) {
    float tmp = p[(size_t)c * STATE_N];
    p[(size_t)c * STATE_N] = run;
    run += tmp;
  }
}

// ---------------------------------------------------------------------------
// Pass 2: per chunk, P = mask(Q K^T) (incl. diagonal), num = P@V + Q@S0,
// den = rowsum(P) + Q.z0, out = num/(den+eps).  grid (NC, BH) x 256 (4 waves).
// ---------------------------------------------------------------------------
__global__ __launch_bounds__(256) void attn_pass2(
    const bf16* __restrict__ qb, const bf16* __restrict__ kb,
    const bf16* __restrict__ vb, const float* __restrict__ states,
    bf16* __restrict__ ao) {
  constexpr int LD = 88;
  __shared__ bf16 Ql[CHUNK * LD];
  __shared__ bf16 Kl[CHUNK * LD];
  __shared__ bf16 VT[DH * LD];    // VT[e][j] = V[j][e]
  __shared__ bf16 S0T[DH * LD];   // S0T[e][d] = S0[d][e]
  __shared__ bf16 Pl[CHUNK * LD]; // masked P, row-major [t][j]
  __shared__ float denl[CHUNK];
  __shared__ float z0l[DH];
  const int tid = threadIdx.x;
  const int wave = tid >> 6, lane = tid & 63;
  const int quad = lane >> 4, l16 = lane & 15;
  const int c = blockIdx.x, bh = blockIdx.y;
  const int b = bh >> 4, h = bh & 15;
  const size_t gbase = ((size_t)(b * S_ + c * CHUNK)) * D_ + h * DH;

#pragma unroll
  for (int rep = 0; rep < 2; rep++) {
    int flat = tid + rep * 256;
    int r = flat >> 3, sg = (flat & 7) * 8;
    *(bf16x8*)&Ql[r * LD + sg] = *(const bf16x8*)(qb + gbase + (size_t)r * D_ + sg);
    *(bf16x8*)&Kl[r * LD + sg] = *(const bf16x8*)(kb + gbase + (size_t)r * D_ + sg);
    bf16x8 vv = *(const bf16x8*)(vb + gbase + (size_t)r * D_ + sg);
#pragma unroll
    for (int u = 0; u < 8; u++) VT[(sg + u) * LD + r] = vv[u];
  }
  const float* st = states + ((size_t)bh * NC + c) * STATE_N;
  for (int f = tid; f < 4096; f += 256) S0T[(f & 63) * LD + (f >> 6)] = (bf16)st[f];
  if (tid < DH) z0l[tid] = st[4096 + tid];
  __syncthreads();

  // phase 1: P = Q K^T
  v4f zero = {0.f, 0.f, 0.f, 0.f};
  v4f pacc[4];
#pragma unroll
  for (int j = 0; j < 4; j++) pacc[j] = zero;
#pragma unroll
  for (int ks = 0; ks < 2; ks++) {
    bf16x8 aq = *(const bf16x8*)&Ql[(wave * 16 + l16) * LD + ks * 32 + quad * 8];
#pragma unroll
    for (int j = 0; j < 4; j++) {
      bf16x8 bk = *(const bf16x8*)&Kl[(j * 16 + l16) * LD + ks * 32 + quad * 8];
      pacc[j] = MFMA16(aq, bk, pacc[j]);
    }
  }
  float rs[4] = {0.f, 0.f, 0.f, 0.f};
#pragma unroll
  for (int j = 0; j < 4; j++) {
#pragma unroll
    for (int r = 0; r < 4; r++) {
      int t = wave * 16 + quad * 4 + r;
      int col = j * 16 + l16;
      float p = (col <= t) ? pacc[j][r] : 0.f;
      Pl[t * LD + col] = (bf16)p;
      rs[r] += p;
    }
  }
#pragma unroll
  for (int m = 1; m < 16; m <<= 1)
#pragma unroll
    for (int r = 0; r < 4; r++) rs[r] += __shfl_xor(rs[r], m, 64);
  if (l16 == 0)
#pragma unroll
    for (int r = 0; r < 4; r++) denl[wave * 16 + quad * 4 + r] = rs[r];
  __syncthreads();
  if (tid < CHUNK) {
    float qz = 0.f;
    for (int d = 0; d < DH; d++) qz += (float)Ql[tid * LD + d] * z0l[d];
    denl[tid] += qz;
  }
  __syncthreads();

  // phase 2: num = P@V + Q@S0
  v4f nacc[4];
#pragma unroll
  for (int j = 0; j < 4; j++) nacc[j] = zero;
#pragma unroll
  for (int ks = 0; ks < 2; ks++) {
    bf16x8 ap = *(const bf16x8*)&Pl[(wave * 16 + l16) * LD + ks * 32 + quad * 8];
#pragma unroll
    for (int j = 0; j < 4; j++) {
      bf16x8 bv = *(const bf16x8*)&VT[(j * 16 + l16) * LD + ks * 32 + quad * 8];
      nacc[j] = MFMA16(ap, bv, nacc[j]);
    }
  }
#pragma unroll
  for (int ks = 0; ks < 2; ks++) {
    bf16x8 aq = *(const bf16x8*)&Ql[(wave * 16 + l16) * LD + ks * 32 + quad * 8];
#pragma unroll
    for (int j = 0; j < 4; j++) {
      bf16x8 bs = *(const bf16x8*)&S0T[(j * 16 + l16) * LD + ks * 32 + quad * 8];
      nacc[j] = MFMA16(aq, bs, nacc[j]);
    }
  }
#pragma unroll
  for (int j = 0; j < 4; j++) {
#pragma unroll
    for (int r = 0; r < 4; r++) {
      int t = wave * 16 + quad * 4 + r;
      int e = j * 16 + l16;
      float o = nacc[j][r] / (denl[t] + EPS);
      ao[gbase + (size_t)t * D_ + e] = (bf16)o;
    }
  }
}

// ---------------------------------------------------------------------------
extern "C" void kernel_launch(void* const* d_in, const int* in_sizes, int n_in,
                              void* d_out, int out_size, void* d_ws, size_t ws_size,
                              hipStream_t stream) {
  const float* x  = (const float*)d_in[0];
  const float* sc = (const float*)d_in[1];
  const float* Wq = (const float*)d_in[2];
  const float* Wk = (const float*)d_in[3];
  const float* Wv = (const float*)d_in[4];
  const float* Wo = (const float*)d_in[5];
  float* out = (float*)d_out;

  const size_t MSZ = (size_t)B_ * S_ * D_;  // 16,777,216 elems
  const size_t WSZ = (size_t)D_ * D_;       // 1,048,576 elems
  bf16* xb = (bf16*)d_ws;
  bf16* qb = xb + MSZ;
  bf16* kb = qb + MSZ;
  bf16* vb = kb + MSZ;
  bf16* ao = vb + MSZ;
  bf16* wt = ao + MSZ;  // 4 transposed bf16 weight matrices [q|k|v|o]
  float* states = (float*)(wt + 4 * WSZ);  // BH*NC*4160 fp32 (~68 MB)

  cvt_f32_bf16<<<MSZ / (256 * 8), 256, 0, stream>>>(x, xb);
  transpose_w4<<<dim3(32, 32, 4), 256, 0, stream>>>(Wq, Wk, Wv, Wo, wt);

  // fused QKV GEMM: BT rows 0..3071 span wt[q|k|v]
  gemm_nt<<<dim3(128, 24), 256, 0, stream>>>(xb, wt, qb, kb, vb, nullptr);

  chunk_kv<<<dim3(NC, BH), 256, 0, stream>>>(kb, vb, states);
  state_prefix<<<dim3(BH, 17), 256, 0, stream>>>(sc, states);
  attn_pass2<<<dim3(NC, BH), 256, 0, stream>>>(qb, kb, vb, states, ao);

  gemm_nt<<<dim3(128, 8), 256, 0, stream>>>(ao, wt + 3 * WSZ, nullptr, nullptr,
                                            nullptr, out);
}